// Round 19
// baseline (178.941 us; speedup 1.0000x reference)
//
#include <hip/hip_runtime.h>
#include <hip/hip_bf16.h>

#define NN 10000
#define NE 320000
#define FDIM 128
#define NRBF 20
#define PHI_DIM 384
#define NBUCK 16
#define NKEY (NN * NBUCK)       // 160000, key = bucket*NN + i (bucket-major)
#define SCAN_BLOCKS 626         // 626*256 = 160256 >= NKEY+1

typedef unsigned int uint;
typedef unsigned short ushort;

#if __has_builtin(__builtin_amdgcn_fdot2_f32_bf16)
#define USE_DOT2 1
typedef __bf16 bf16x2 __attribute__((ext_vector_type(2)));
#else
#define USE_DOT2 0
#endif

__device__ __forceinline__ ushort f2bf(float x) {
  __hip_bfloat16 b = __float2bfloat16(x);
  return *(ushort*)&b;
}
__device__ __forceinline__ float bflo(uint u) { return __uint_as_float(u << 16); }
__device__ __forceinline__ float bfhi(uint u) { return __uint_as_float(u & 0xffff0000u); }
__device__ __forceinline__ int jbucket(int j) { return (int)(((uint)j * NBUCK) / NN); }

// tab row (1280 B): [0,512) uint wy|wx ; [512,1024) uint phi1|wz ; [1024,1280) ushort phi2
// edata record (48 B): dword0 = dy|dx ; dword1..10 = (rbf*c) pairs ; dword11 = dz|c
//   (node-side wr pair10 = (br_col, 0) -> dot2 yields br*c; dz rides in high half)
// offsets[] PARTIAL (within-scan1-block); final = offsets[k] + blocksums[k>>8];
// offsets[NKEY] written FINAL by scan2.

// ------- node MLP: 256 thr/block, two 128-thread halves x 4 nodes (1250 blocks) -------
__global__ __launch_bounds__(256) void phi_kernel(
    const float* __restrict__ S, const float* __restrict__ W1, const float* __restrict__ b1,
    const float* __restrict__ W2, const float* __restrict__ b2, const float* __restrict__ vf,
    const int* __restrict__ idx_i, const int* __restrict__ idx_j, int* __restrict__ counts,
    char* __restrict__ tab) {
  __shared__ float s_s[8][FDIM];
  __shared__ float h_s[8][FDIM];
  const int t = threadIdx.x;
  const int tf = t & 127;
  const int half = t >> 7;
  const int nb = blockIdx.x * 8 + half * 4;
  const int row0 = half * 4;
  // fused: edge counting over bucket-major keys (1 edge per thread: 1250*256 == NE)
  {
    const int e = blockIdx.x * 256 + t;
    atomicAdd(&counts[jbucket(idx_j[e]) * NN + idx_i[e]], 1);
  }
#pragma unroll
  for (int n = 0; n < 4; n++) s_s[row0 + n][tf] = S[(nb + n) * FDIM + tf];
  __syncthreads();
  float acc[4];
#pragma unroll
  for (int n = 0; n < 4; n++) acc[n] = 0.f;
  for (int k = 0; k < FDIM; k++) {
    float w = W1[k * FDIM + tf];
#pragma unroll
    for (int n = 0; n < 4; n++) acc[n] += s_s[row0 + n][k] * w;
  }
  float bb = b1[tf];
#pragma unroll
  for (int n = 0; n < 4; n++) {
    float x = acc[n] + bb;
    h_s[row0 + n][tf] = x / (1.0f + expf(-x));
  }
  __syncthreads();
  float a0[4], a1[4], a2[4];
#pragma unroll
  for (int n = 0; n < 4; n++) { a0[n] = 0.f; a1[n] = 0.f; a2[n] = 0.f; }
  for (int k = 0; k < FDIM; k++) {
    float w0 = W2[k * PHI_DIM + tf];
    float w1 = W2[k * PHI_DIM + tf + 128];
    float w2 = W2[k * PHI_DIM + tf + 256];
#pragma unroll
    for (int n = 0; n < 4; n++) {
      float hv = h_s[row0 + n][k];
      a0[n] += hv * w0;
      a1[n] += hv * w1;
      a2[n] += hv * w2;
    }
  }
  float c0 = b2[tf], c1 = b2[tf + 128], c2 = b2[tf + 256];
#pragma unroll
  for (int n = 0; n < 4; n++) {
    const int node = nb + n;
    const float p0 = a0[n] + c0;
    const float p1 = a1[n] + c1;
    const float p2 = a2[n] + c2;
    const float* src = vf + (size_t)node * (FDIM * 3) + tf * 3;
    const uint wx = f2bf(src[0] * p0);
    const uint wy = f2bf(src[1] * p0);
    const uint wz = f2bf(src[2] * p0);
    char* pb = tab + (size_t)node * 1280;
    ((uint*)pb)[tf] = (wy << 16) | wx;
    ((uint*)(pb + 512))[tf] = ((uint)f2bf(p1) << 16) | wz;
    ((ushort*)(pb + 1024))[tf] = f2bf(p2);
  }
}

// ---------------- scan: per-block partials + block-sum scan ----------------
__global__ void scan1_kernel(const int* __restrict__ counts, int* __restrict__ offsets,
                             int* __restrict__ blocksums) {
  __shared__ int s[256];
  const int t = threadIdx.x;
  const int idx = blockIdx.x * 256 + t;
  const int c = counts[idx];  // region zero-padded to 160256
  s[t] = c;
  __syncthreads();
  for (int off = 1; off < 256; off <<= 1) {
    int v = (t >= off) ? s[t - off] : 0;
    __syncthreads();
    s[t] += v;
    __syncthreads();
  }
  if (idx < NKEY) offsets[idx] = s[t] - c;  // exclusive WITHIN block (partial)
  if (t == 255) blocksums[blockIdx.x] = s[255];
}

__global__ void scan2_kernel(int* __restrict__ blocksums, int* __restrict__ offsets) {
  __shared__ int s[1024];
  const int t = threadIdx.x;  // 1024 threads
  int v0 = (t < SCAN_BLOCKS) ? blocksums[t] : 0;
  s[t] = v0;
  __syncthreads();
  for (int off = 1; off < 1024; off <<= 1) {
    int v = (t >= off) ? s[t - off] : 0;
    __syncthreads();
    s[t] += v;
    __syncthreads();
  }
  if (t < SCAN_BLOCKS) blocksums[t] = s[t] - v0;  // exclusive base per block
  if (t == 1023) offsets[NKEY] = s[t];            // FINAL total = NE
}

// ---------------- stage CSR-ordered (bucket-major): jlist + 48-B records ----------------
__global__ void stage_kernel(const int* __restrict__ idx_i, const int* __restrict__ idx_j,
                             const float* __restrict__ cut, const float* __restrict__ dir,
                             const float* __restrict__ rbf, const int* __restrict__ offsets,
                             const int* __restrict__ blocksums, int* __restrict__ counts,
                             uint* __restrict__ edata, int* __restrict__ jlist) {
  int e = blockIdx.x * blockDim.x + threadIdx.x;
  if (e >= NE) return;
  const int j = idx_j[e];
  const int key = jbucket(j) * NN + idx_i[e];
  int pos = atomicSub(&counts[key], 1) - 1;
  const int slot = offsets[key] + blocksums[key >> 8] + pos;
  jlist[slot] = j;
  const float c = cut[e];
  uint w[12];
  w[0] = ((uint)f2bf(dir[e * 3 + 1]) << 16) | f2bf(dir[e * 3 + 0]);
  const float* rb = rbf + (size_t)e * NRBF;
#pragma unroll
  for (int r = 0; r < 10; r++) {
    uint lo = (uint)f2bf(rb[2 * r] * c);
    uint hi = (uint)f2bf(rb[2 * r + 1] * c);
    w[1 + r] = (hi << 16) | lo;
  }
  w[11] = ((uint)f2bf(dir[e * 3 + 2]) << 16) | f2bf(c);
  uint4* d = (uint4*)(edata + (size_t)slot * 12);
  d[0] = make_uint4(w[0], w[1], w[2], w[3]);
  d[1] = make_uint4(w[4], w[5], w[6], w[7]);
  d[2] = make_uint4(w[8], w[9], w[10], w[11]);
}

// ---- node: 2000 persistent co-resident blocks x 5 nodes, bucket-major sweep ----
__global__ __launch_bounds__(128, 4) void node_kernel(
    const uint* __restrict__ edata, const int* __restrict__ jlist,
    const float* __restrict__ Wr, const float* __restrict__ br,
    const char* __restrict__ tab, const float* __restrict__ sf,
    const float* __restrict__ vf, const int* __restrict__ offsets,
    const int* __restrict__ blocksums, float* __restrict__ out) {
  const int f = threadIdx.x;  // 0..127
#if USE_DOT2
  bf16x2 wrA[11], wrB[11], wrC[11];
#pragma unroll
  for (int r = 0; r < 10; r++) {
    uint a = ((uint)f2bf(Wr[(2 * r + 1) * PHI_DIM + f]) << 16) | f2bf(Wr[(2 * r) * PHI_DIM + f]);
    uint b = ((uint)f2bf(Wr[(2 * r + 1) * PHI_DIM + f + 128]) << 16) |
             f2bf(Wr[(2 * r) * PHI_DIM + f + 128]);
    uint c = ((uint)f2bf(Wr[(2 * r + 1) * PHI_DIM + f + 256]) << 16) |
             f2bf(Wr[(2 * r) * PHI_DIM + f + 256]);
    wrA[r] = __builtin_bit_cast(bf16x2, a);
    wrB[r] = __builtin_bit_cast(bf16x2, b);
    wrC[r] = __builtin_bit_cast(bf16x2, c);
  }
  wrA[10] = __builtin_bit_cast(bf16x2, (uint)f2bf(br[f]));
  wrB[10] = __builtin_bit_cast(bf16x2, (uint)f2bf(br[f + 128]));
  wrC[10] = __builtin_bit_cast(bf16x2, (uint)f2bf(br[f + 256]));
#else
  float wrA[22], wrB[22], wrC[22];
#pragma unroll
  for (int r = 0; r < NRBF; r++) {
    wrA[r] = Wr[r * PHI_DIM + f];
    wrB[r] = Wr[r * PHI_DIM + f + 128];
    wrC[r] = Wr[r * PHI_DIM + f + 256];
  }
  wrA[20] = br[f];       wrA[21] = 0.f;
  wrB[20] = br[f + 128]; wrB[21] = 0.f;
  wrC[20] = br[f + 256]; wrC[21] = 0.f;
#endif
  const int n0 = blockIdx.x * 5;
  const int f4 = f * 4;
  float ss0 = 0, ax0 = 0, ay0 = 0, az0 = 0;
  float ss1 = 0, ax1 = 0, ay1 = 0, az1 = 0;
  float ss2 = 0, ax2 = 0, ay2 = 0, az2 = 0;
  float ss3 = 0, ax3 = 0, ay3 = 0, az3 = 0;
  float ss4 = 0, ax4 = 0, ay4 = 0, az4 = 0;
  int c0n = 0, c1n = 0, c2n = 0, c3n = 0, c4n = 0;

  auto runSeg = [&](int segBeg, int segEnd, float& ss, float& ax, float& ay, float& az) {
    auto process = [&](uint4 e0, uint4 e1, uint4 e2, uint d0, uint d1, uint zu) {
      uint rbp[11] = {e0.y, e0.z, e0.w, e1.x, e1.y, e1.z, e1.w, e2.x, e2.y, e2.z, e2.w};
      const float dx = bflo(e0.x);
      const float dy = bfhi(e0.x);
      const float dz = bfhi(rbp[10]);
      float g0 = 0.f, g1 = 0.f, g2 = 0.f;
#if USE_DOT2
#pragma unroll
      for (int r = 0; r < 11; r++) {
        bf16x2 rp = __builtin_bit_cast(bf16x2, rbp[r]);
        g0 = __builtin_amdgcn_fdot2_f32_bf16(rp, wrA[r], g0, false);
        g1 = __builtin_amdgcn_fdot2_f32_bf16(rp, wrB[r], g1, false);
        g2 = __builtin_amdgcn_fdot2_f32_bf16(rp, wrC[r], g2, false);
      }
#else
#pragma unroll
      for (int r = 0; r < 11; r++) {
        float rlo = bflo(rbp[r]);
        float rhi = bfhi(rbp[r]);
        g0 += rlo * wrA[2 * r] + rhi * wrA[2 * r + 1];
        g1 += rlo * wrB[2 * r] + rhi * wrB[2 * r + 1];
        g2 += rlo * wrC[2 * r] + rhi * wrC[2 * r + 1];
      }
#endif
      const float vs = bflo(zu) * g2;
      ss += bfhi(d1) * g1;
      ax += bflo(d0) * g0 + vs * dx;
      ay += bfhi(d0) * g0 + vs * dy;
      az += bflo(d1) * g0 + vs * dz;
    };
    int p = segBeg;
    for (; p + 2 <= segEnd; p += 2) {
      const int j0 = __builtin_amdgcn_readfirstlane(jlist[p]);
      const int j1 = __builtin_amdgcn_readfirstlane(jlist[p + 1]);
      const char* B0 = tab + (size_t)j0 * 1280;
      const char* B1 = tab + (size_t)j1 * 1280;
      const uint d00 = *(const uint*)(B0 + f4), d01 = *(const uint*)(B0 + 512 + f4);
      const uint z0 = *(const ushort*)(B0 + 1024 + f * 2);
      const uint d10 = *(const uint*)(B1 + f4), d11 = *(const uint*)(B1 + 512 + f4);
      const uint z1 = *(const ushort*)(B1 + 1024 + f * 2);
      const uint4* r0 = (const uint4*)(edata + (size_t)p * 12);
      const uint4* r1 = (const uint4*)(edata + (size_t)(p + 1) * 12);
      uint4 a0 = r0[0], a1 = r0[1], a2 = r0[2];
      uint4 b0 = r1[0], b1 = r1[1], b2 = r1[2];
      process(a0, a1, a2, d00, d01, z0);
      process(b0, b1, b2, d10, d11, z1);
    }
    if (p < segEnd) {
      const int j0 = __builtin_amdgcn_readfirstlane(jlist[p]);
      const char* B0 = tab + (size_t)j0 * 1280;
      const uint d00 = *(const uint*)(B0 + f4), d01 = *(const uint*)(B0 + 512 + f4);
      const uint z0 = *(const ushort*)(B0 + 1024 + f * 2);
      const uint4* r0 = (const uint4*)(edata + (size_t)p * 12);
      process(r0[0], r0[1], r0[2], d00, d01, z0);
    }
  };

  for (int b = 0; b < NBUCK; b++) {
    const int base = b * NN + n0;
    int o[6];
#pragma unroll
    for (int q = 0; q < 6; q++) {
      const int key = base + q;
      o[q] = __builtin_amdgcn_readfirstlane(
          (key < NKEY) ? (offsets[key] + blocksums[key >> 8]) : offsets[NKEY]);
    }
    runSeg(o[0], o[1], ss0, ax0, ay0, az0);
    runSeg(o[1], o[2], ss1, ax1, ay1, az1);
    runSeg(o[2], o[3], ss2, ax2, ay2, az2);
    runSeg(o[3], o[4], ss3, ax3, ay3, az3);
    runSeg(o[4], o[5], ss4, ax4, ay4, az4);
    c0n += o[1] - o[0];
    c1n += o[2] - o[1];
    c2n += o[3] - o[2];
    c3n += o[4] - o[3];
    c4n += o[5] - o[4];
  }

  auto writeOut = [&](int s, int cnt, float ss, float ax, float ay, float az) {
    const int i = n0 + s;
    const float inv = 1.0f / (float)cnt;
    out[(size_t)i * FDIM + f] = sf[(size_t)i * FDIM + f] + ss * inv;
    float* ov = out + (size_t)NN * FDIM + (size_t)i * (FDIM * 3) + f * 3;
    const float* iv = vf + (size_t)i * (FDIM * 3) + f * 3;
    ov[0] = iv[0] + ax * inv;
    ov[1] = iv[1] + ay * inv;
    ov[2] = iv[2] + az * inv;
  };
  writeOut(0, c0n, ss0, ax0, ay0, az0);
  writeOut(1, c1n, ss1, ax1, ay1, az1);
  writeOut(2, c2n, ss2, ax2, ay2, az2);
  writeOut(3, c3n, ss3, ax3, ay3, az3);
  writeOut(4, c4n, ss4, ax4, ay4, az4);
}

extern "C" void kernel_launch(void* const* d_in, const int* in_sizes, int n_in,
                              void* d_out, int out_size, void* d_ws, size_t ws_size,
                              hipStream_t stream) {
  const int* idx_i = (const int*)d_in[0];
  const int* idx_j = (const int*)d_in[1];
  const float* rel_dir = (const float*)d_in[2];
  const float* cut = (const float*)d_in[3];
  const float* rbf = (const float*)d_in[4];
  const float* sf = (const float*)d_in[5];
  const float* vf = (const float*)d_in[6];
  const float* W1 = (const float*)d_in[7];
  const float* b1 = (const float*)d_in[8];
  const float* W2 = (const float*)d_in[9];
  const float* b2 = (const float*)d_in[10];
  const float* Wr = (const float*)d_in[11];
  const float* br = (const float*)d_in[12];
  float* out = (float*)d_out;

  // workspace layout (bytes):
  //   counts   : [0, 641024)            160256 ints (zero-padded; consumed by stage)
  //   offsets  : [641024, 1281088)      160001 ints (PARTIAL; +blocksums[k>>8])
  //   blocksums: [1281088, 1283648)     626 ints (padded)
  //   edata    : [1283648, 16643648)    320000 * 48 B
  //   tab      : [16643648, 29443648)   10000 * 1280 B
  //   jlist    : [29443648, 30723648)   320000 ints
  char* w = (char*)d_ws;
  int* counts = (int*)w;
  int* offsets = (int*)(w + 641024);
  int* blocksums = (int*)(w + 1281088);
  uint* edata = (uint*)(w + 1283648);
  char* tab = w + 16643648;
  int* jlist = (int*)(w + 29443648);

  hipMemsetAsync(w, 0, 641024, stream);  // zero counts only
  hipLaunchKernelGGL(phi_kernel, dim3(NN / 8), dim3(256), 0, stream, sf, W1, b1, W2, b2, vf,
                     idx_i, idx_j, counts, tab);
  hipLaunchKernelGGL(scan1_kernel, dim3(SCAN_BLOCKS), dim3(256), 0, stream, counts, offsets,
                     blocksums);
  hipLaunchKernelGGL(scan2_kernel, dim3(1), dim3(1024), 0, stream, blocksums, offsets);
  hipLaunchKernelGGL(stage_kernel, dim3((NE + 255) / 256), dim3(256), 0, stream, idx_i, idx_j,
                     cut, rel_dir, rbf, offsets, blocksums, counts, edata, jlist);
  hipLaunchKernelGGL(node_kernel, dim3(NN / 5), dim3(128), 0, stream, edata, jlist, Wr, br, tab,
                     sf, vf, offsets, blocksums, out);
}

// Round 20
// 153.616 us; speedup vs baseline: 1.1649x; 1.1649x over previous
//
#include <hip/hip_runtime.h>
#include <hip/hip_bf16.h>

#define NN 10000
#define NE 320000
#define FDIM 128
#define NRBF 20
#define PHI_DIM 384
#define NBUCK 4
#define NKEY (NN * NBUCK)     // 40000, key = bucket*NN + i (bucket-major)
#define SCAN_BLOCKS 157       // 157*256 = 40192 >= NKEY+1

typedef unsigned int uint;
typedef unsigned short ushort;

#if __has_builtin(__builtin_amdgcn_fdot2_f32_bf16)
#define USE_DOT2 1
typedef __bf16 bf16x2 __attribute__((ext_vector_type(2)));
#else
#define USE_DOT2 0
#endif

__device__ __forceinline__ ushort f2bf(float x) {
  __hip_bfloat16 b = __float2bfloat16(x);
  return *(ushort*)&b;
}
__device__ __forceinline__ float bflo(uint u) { return __uint_as_float(u << 16); }
__device__ __forceinline__ float bfhi(uint u) { return __uint_as_float(u & 0xffff0000u); }
__device__ __forceinline__ int jbucket(int j) { return (int)(((uint)j * NBUCK) / NN); }

// tab row (1280 B): [0,512) uint wy|wx ; [512,1024) uint phi1|wz ; [1024,1280) ushort phi2
// edata record (48 B): dword0 = dy|dx ; dword1..10 = (rbf*c) pairs ; dword11 = dz|c
//   (node-side wr pair10 = (br_col, 0) -> dot2 yields br*c; dz rides in high half)
// offsets[] PARTIAL (within-scan1-block); final = offsets[k] + blocksums[k>>8];
// offsets[NKEY] written FINAL by scan2.

// ------- node MLP: 256 thr/block, two 128-thread halves x 4 nodes (1250 blocks) -------
__global__ __launch_bounds__(256) void phi_kernel(
    const float* __restrict__ S, const float* __restrict__ W1, const float* __restrict__ b1,
    const float* __restrict__ W2, const float* __restrict__ b2, const float* __restrict__ vf,
    const int* __restrict__ idx_i, const int* __restrict__ idx_j, int* __restrict__ counts,
    char* __restrict__ tab) {
  __shared__ float s_s[8][FDIM];
  __shared__ float h_s[8][FDIM];
  const int t = threadIdx.x;
  const int tf = t & 127;
  const int half = t >> 7;
  const int nb = blockIdx.x * 8 + half * 4;
  const int row0 = half * 4;
  // fused: edge counting over bucket-major keys (1 edge per thread: 1250*256 == NE)
  {
    const int e = blockIdx.x * 256 + t;
    atomicAdd(&counts[jbucket(idx_j[e]) * NN + idx_i[e]], 1);
  }
#pragma unroll
  for (int n = 0; n < 4; n++) s_s[row0 + n][tf] = S[(nb + n) * FDIM + tf];
  __syncthreads();
  float acc[4];
#pragma unroll
  for (int n = 0; n < 4; n++) acc[n] = 0.f;
  for (int k = 0; k < FDIM; k++) {
    float w = W1[k * FDIM + tf];
#pragma unroll
    for (int n = 0; n < 4; n++) acc[n] += s_s[row0 + n][k] * w;
  }
  float bb = b1[tf];
#pragma unroll
  for (int n = 0; n < 4; n++) {
    float x = acc[n] + bb;
    h_s[row0 + n][tf] = x / (1.0f + expf(-x));
  }
  __syncthreads();
  float a0[4], a1[4], a2[4];
#pragma unroll
  for (int n = 0; n < 4; n++) { a0[n] = 0.f; a1[n] = 0.f; a2[n] = 0.f; }
  for (int k = 0; k < FDIM; k++) {
    float w0 = W2[k * PHI_DIM + tf];
    float w1 = W2[k * PHI_DIM + tf + 128];
    float w2 = W2[k * PHI_DIM + tf + 256];
#pragma unroll
    for (int n = 0; n < 4; n++) {
      float hv = h_s[row0 + n][k];
      a0[n] += hv * w0;
      a1[n] += hv * w1;
      a2[n] += hv * w2;
    }
  }
  float c0 = b2[tf], c1 = b2[tf + 128], c2 = b2[tf + 256];
#pragma unroll
  for (int n = 0; n < 4; n++) {
    const int node = nb + n;
    const float p0 = a0[n] + c0;
    const float p1 = a1[n] + c1;
    const float p2 = a2[n] + c2;
    const float* src = vf + (size_t)node * (FDIM * 3) + tf * 3;
    const uint wx = f2bf(src[0] * p0);
    const uint wy = f2bf(src[1] * p0);
    const uint wz = f2bf(src[2] * p0);
    char* pb = tab + (size_t)node * 1280;
    ((uint*)pb)[tf] = (wy << 16) | wx;
    ((uint*)(pb + 512))[tf] = ((uint)f2bf(p1) << 16) | wz;
    ((ushort*)(pb + 1024))[tf] = f2bf(p2);
  }
}

// ---------------- scan: per-block partials + block-sum scan ----------------
__global__ void scan1_kernel(const int* __restrict__ counts, int* __restrict__ offsets,
                             int* __restrict__ blocksums) {
  __shared__ int s[256];
  const int t = threadIdx.x;
  const int idx = blockIdx.x * 256 + t;
  const int c = counts[idx];  // region zero-padded to 40960
  s[t] = c;
  __syncthreads();
  for (int off = 1; off < 256; off <<= 1) {
    int v = (t >= off) ? s[t - off] : 0;
    __syncthreads();
    s[t] += v;
    __syncthreads();
  }
  if (idx < NKEY) offsets[idx] = s[t] - c;  // exclusive WITHIN block (partial)
  if (t == 255) blocksums[blockIdx.x] = s[255];
}

__global__ void scan2_kernel(int* __restrict__ blocksums, int* __restrict__ offsets) {
  __shared__ int s[256];
  const int t = threadIdx.x;  // 256 threads
  int v0 = (t < SCAN_BLOCKS) ? blocksums[t] : 0;
  s[t] = v0;
  __syncthreads();
  for (int off = 1; off < 256; off <<= 1) {
    int v = (t >= off) ? s[t - off] : 0;
    __syncthreads();
    s[t] += v;
    __syncthreads();
  }
  if (t < SCAN_BLOCKS) blocksums[t] = s[t] - v0;  // exclusive base per block
  if (t == 255) offsets[NKEY] = s[t];             // FINAL total = NE
}

// ---------------- stage CSR-ordered (bucket-major): jlist + 48-B records ----------------
__global__ void stage_kernel(const int* __restrict__ idx_i, const int* __restrict__ idx_j,
                             const float* __restrict__ cut, const float* __restrict__ dir,
                             const float* __restrict__ rbf, const int* __restrict__ offsets,
                             const int* __restrict__ blocksums, int* __restrict__ counts,
                             uint* __restrict__ edata, int* __restrict__ jlist) {
  int e = blockIdx.x * blockDim.x + threadIdx.x;
  if (e >= NE) return;
  const int j = idx_j[e];
  const int key = jbucket(j) * NN + idx_i[e];
  int pos = atomicSub(&counts[key], 1) - 1;
  const int slot = offsets[key] + blocksums[key >> 8] + pos;
  jlist[slot] = j;
  const float c = cut[e];
  uint w[12];
  w[0] = ((uint)f2bf(dir[e * 3 + 1]) << 16) | f2bf(dir[e * 3 + 0]);
  const float* rb = rbf + (size_t)e * NRBF;
#pragma unroll
  for (int r = 0; r < 10; r++) {
    uint lo = (uint)f2bf(rb[2 * r] * c);
    uint hi = (uint)f2bf(rb[2 * r + 1] * c);
    w[1 + r] = (hi << 16) | lo;
  }
  w[11] = ((uint)f2bf(dir[e * 3 + 2]) << 16) | f2bf(c);
  uint4* d = (uint4*)(edata + (size_t)slot * 12);
  d[0] = make_uint4(w[0], w[1], w[2], w[3]);
  d[1] = make_uint4(w[4], w[5], w[6], w[7]);
  d[2] = make_uint4(w[8], w[9], w[10], w[11]);
}

// ---- node: 1 node / 128-thread block, 4 bucket-segments, 2-deep pipeline ----
__global__ __launch_bounds__(128, 5) void node_kernel(
    const uint* __restrict__ edata, const int* __restrict__ jlist,
    const float* __restrict__ Wr, const float* __restrict__ br,
    const char* __restrict__ tab, const float* __restrict__ sf,
    const float* __restrict__ vf, const int* __restrict__ offsets,
    const int* __restrict__ blocksums, float* __restrict__ out) {
  const int f = threadIdx.x;  // 0..127
#if USE_DOT2
  bf16x2 wrA[11], wrB[11], wrC[11];
#pragma unroll
  for (int r = 0; r < 10; r++) {
    uint a = ((uint)f2bf(Wr[(2 * r + 1) * PHI_DIM + f]) << 16) | f2bf(Wr[(2 * r) * PHI_DIM + f]);
    uint b = ((uint)f2bf(Wr[(2 * r + 1) * PHI_DIM + f + 128]) << 16) |
             f2bf(Wr[(2 * r) * PHI_DIM + f + 128]);
    uint c = ((uint)f2bf(Wr[(2 * r + 1) * PHI_DIM + f + 256]) << 16) |
             f2bf(Wr[(2 * r) * PHI_DIM + f + 256]);
    wrA[r] = __builtin_bit_cast(bf16x2, a);
    wrB[r] = __builtin_bit_cast(bf16x2, b);
    wrC[r] = __builtin_bit_cast(bf16x2, c);
  }
  wrA[10] = __builtin_bit_cast(bf16x2, (uint)f2bf(br[f]));
  wrB[10] = __builtin_bit_cast(bf16x2, (uint)f2bf(br[f + 128]));
  wrC[10] = __builtin_bit_cast(bf16x2, (uint)f2bf(br[f + 256]));
#else
  float wrA[22], wrB[22], wrC[22];
#pragma unroll
  for (int r = 0; r < NRBF; r++) {
    wrA[r] = Wr[r * PHI_DIM + f];
    wrB[r] = Wr[r * PHI_DIM + f + 128];
    wrC[r] = Wr[r * PHI_DIM + f + 256];
  }
  wrA[20] = br[f];       wrA[21] = 0.f;
  wrB[20] = br[f + 128]; wrB[21] = 0.f;
  wrC[20] = br[f + 256]; wrC[21] = 0.f;
#endif
  const int n = blockIdx.x;
  const int f4 = f * 4;
  float ss = 0.f, ax = 0.f, ay = 0.f, az = 0.f;
  int cnt = 0;

  auto process = [&](uint4 e0, uint4 e1, uint4 e2, uint d0, uint d1, uint zu) {
    uint rbp[11] = {e0.y, e0.z, e0.w, e1.x, e1.y, e1.z, e1.w, e2.x, e2.y, e2.z, e2.w};
    const float dx = bflo(e0.x);
    const float dy = bfhi(e0.x);
    const float dz = bfhi(rbp[10]);
    float g0 = 0.f, g1 = 0.f, g2 = 0.f;
#if USE_DOT2
#pragma unroll
    for (int r = 0; r < 11; r++) {
      bf16x2 rp = __builtin_bit_cast(bf16x2, rbp[r]);
      g0 = __builtin_amdgcn_fdot2_f32_bf16(rp, wrA[r], g0, false);
      g1 = __builtin_amdgcn_fdot2_f32_bf16(rp, wrB[r], g1, false);
      g2 = __builtin_amdgcn_fdot2_f32_bf16(rp, wrC[r], g2, false);
    }
#else
#pragma unroll
    for (int r = 0; r < 11; r++) {
      float rlo = bflo(rbp[r]);
      float rhi = bfhi(rbp[r]);
      g0 += rlo * wrA[2 * r] + rhi * wrA[2 * r + 1];
      g1 += rlo * wrB[2 * r] + rhi * wrB[2 * r + 1];
      g2 += rlo * wrC[2 * r] + rhi * wrC[2 * r + 1];
    }
#endif
    const float vs = bflo(zu) * g2;
    ss += bfhi(d1) * g1;
    ax += bflo(d0) * g0 + vs * dx;
    ay += bfhi(d0) * g0 + vs * dy;
    az += bflo(d1) * g0 + vs * dz;
  };

  for (int b = 0; b < NBUCK; b++) {
    const int k0 = b * NN + n;
    const int beg = __builtin_amdgcn_readfirstlane(offsets[k0] + blocksums[k0 >> 8]);
    const int k1 = k0 + 1;
    const int end = __builtin_amdgcn_readfirstlane(
        (k1 < NKEY) ? (offsets[k1] + blocksums[k1 >> 8]) : offsets[NKEY]);
    cnt += end - beg;
    int p = beg;
    for (; p + 2 <= end; p += 2) {
      const int j0 = __builtin_amdgcn_readfirstlane(jlist[p]);
      const int j1 = __builtin_amdgcn_readfirstlane(jlist[p + 1]);
      const char* B0 = tab + (size_t)j0 * 1280;
      const char* B1 = tab + (size_t)j1 * 1280;
      const uint d00 = *(const uint*)(B0 + f4), d01 = *(const uint*)(B0 + 512 + f4);
      const uint z0 = *(const ushort*)(B0 + 1024 + f * 2);
      const uint d10 = *(const uint*)(B1 + f4), d11 = *(const uint*)(B1 + 512 + f4);
      const uint z1 = *(const ushort*)(B1 + 1024 + f * 2);
      const uint4* r0 = (const uint4*)(edata + (size_t)p * 12);
      const uint4* r1 = (const uint4*)(edata + (size_t)(p + 1) * 12);
      uint4 a0 = r0[0], a1 = r0[1], a2 = r0[2];
      uint4 b0 = r1[0], b1 = r1[1], b2 = r1[2];
      process(a0, a1, a2, d00, d01, z0);
      process(b0, b1, b2, d10, d11, z1);
    }
    if (p < end) {
      const int j0 = __builtin_amdgcn_readfirstlane(jlist[p]);
      const char* B0 = tab + (size_t)j0 * 1280;
      const uint d00 = *(const uint*)(B0 + f4), d01 = *(const uint*)(B0 + 512 + f4);
      const uint z0 = *(const ushort*)(B0 + 1024 + f * 2);
      const uint4* r0 = (const uint4*)(edata + (size_t)p * 12);
      process(r0[0], r0[1], r0[2], d00, d01, z0);
    }
  }

  const float inv = 1.0f / (float)cnt;
  out[(size_t)n * FDIM + f] = sf[(size_t)n * FDIM + f] + ss * inv;
  float* ov = out + (size_t)NN * FDIM + (size_t)n * (FDIM * 3) + f * 3;
  const float* iv = vf + (size_t)n * (FDIM * 3) + f * 3;
  ov[0] = iv[0] + ax * inv;
  ov[1] = iv[1] + ay * inv;
  ov[2] = iv[2] + az * inv;
}

extern "C" void kernel_launch(void* const* d_in, const int* in_sizes, int n_in,
                              void* d_out, int out_size, void* d_ws, size_t ws_size,
                              hipStream_t stream) {
  const int* idx_i = (const int*)d_in[0];
  const int* idx_j = (const int*)d_in[1];
  const float* rel_dir = (const float*)d_in[2];
  const float* cut = (const float*)d_in[3];
  const float* rbf = (const float*)d_in[4];
  const float* sf = (const float*)d_in[5];
  const float* vf = (const float*)d_in[6];
  const float* W1 = (const float*)d_in[7];
  const float* b1 = (const float*)d_in[8];
  const float* W2 = (const float*)d_in[9];
  const float* b2 = (const float*)d_in[10];
  const float* Wr = (const float*)d_in[11];
  const float* br = (const float*)d_in[12];
  float* out = (float*)d_out;

  // workspace layout (bytes):
  //   counts   : [0, 163840)            40960 ints (zero-padded; consumed by stage)
  //   offsets  : [163840, 327680)       40001 ints (PARTIAL; +blocksums[k>>8])
  //   blocksums: [327680, 328704)       256 ints
  //   edata    : [328704, 15688704)     320000 * 48 B
  //   tab      : [15688704, 28488704)   10000 * 1280 B
  //   jlist    : [28488704, 29768704)   320000 ints
  char* w = (char*)d_ws;
  int* counts = (int*)w;
  int* offsets = (int*)(w + 163840);
  int* blocksums = (int*)(w + 327680);
  uint* edata = (uint*)(w + 328704);
  char* tab = w + 15688704;
  int* jlist = (int*)(w + 28488704);

  hipMemsetAsync(w, 0, 163840, stream);  // zero counts only
  hipLaunchKernelGGL(phi_kernel, dim3(NN / 8), dim3(256), 0, stream, sf, W1, b1, W2, b2, vf,
                     idx_i, idx_j, counts, tab);
  hipLaunchKernelGGL(scan1_kernel, dim3(SCAN_BLOCKS), dim3(256), 0, stream, counts, offsets,
                     blocksums);
  hipLaunchKernelGGL(scan2_kernel, dim3(1), dim3(256), 0, stream, blocksums, offsets);
  hipLaunchKernelGGL(stage_kernel, dim3((NE + 255) / 256), dim3(256), 0, stream, idx_i, idx_j,
                     cut, rel_dir, rbf, offsets, blocksums, counts, edata, jlist);
  hipLaunchKernelGGL(node_kernel, dim3(NN), dim3(128), 0, stream, edata, jlist, Wr, br, tab, sf,
                     vf, offsets, blocksums, out);
}

// Round 21
// 137.553 us; speedup vs baseline: 1.3009x; 1.1168x over previous
//
#include <hip/hip_runtime.h>
#include <hip/hip_bf16.h>

#define NN 10000
#define NE 320000
#define FDIM 128
#define NRBF 20
#define PHI_DIM 384
#define NBUCK 4
#define NKEY (NN * NBUCK)     // 40000, key = bucket*NN + i (bucket-major)
#define SCAN_BLOCKS 157       // 157*256 = 40192 >= NKEY+1

typedef unsigned int uint;
typedef unsigned short ushort;
typedef __bf16 bf16x8 __attribute__((ext_vector_type(8)));
typedef float f32x4 __attribute__((ext_vector_type(4)));

#if __has_builtin(__builtin_amdgcn_fdot2_f32_bf16)
#define USE_DOT2 1
typedef __bf16 bf16x2 __attribute__((ext_vector_type(2)));
#else
#define USE_DOT2 0
#endif

__device__ __forceinline__ ushort f2bf(float x) {
  __hip_bfloat16 b = __float2bfloat16(x);
  return *(ushort*)&b;
}
__device__ __forceinline__ float bflo(uint u) { return __uint_as_float(u << 16); }
__device__ __forceinline__ float bfhi(uint u) { return __uint_as_float(u & 0xffff0000u); }
__device__ __forceinline__ float bf2f(ushort u) { return __uint_as_float(((uint)u) << 16); }
__device__ __forceinline__ int jbucket(int j) { return (int)(((uint)j * NBUCK) / NN); }

// tab row (1280 B): [0,512) uint wy|wx ; [512,1024) uint phi1|wz ; [1024,1280) ushort phi2
// edata record (48 B): dword0 = dy|dx ; dword1..10 = (rbf*c) pairs ; dword11 = dz|c
// offsets[] PARTIAL (within-scan1-block); final = offsets[k] + blocksums[k>>8];
// offsets[NKEY] written FINAL by scan2.
// W1p/W2p: frag-packed bf16 weights: [(ks*4+g)*COLS + n] -> 8 bf16 of rows ks*32+g*8+e.

// ---------------- weight pre-pack: f32 -> frag-friendly bf16 ----------------
__global__ void wconv_kernel(const float* __restrict__ W1, const float* __restrict__ W2,
                             ushort* __restrict__ W1p, ushort* __restrict__ W2p) {
  const int gid = blockIdx.x * 256 + threadIdx.x;  // 8192 total
  if (gid < 2048) {  // W1: 4*4*128 groups
    const int n = gid & 127, g = (gid >> 7) & 3, ks = gid >> 9;
    ushort* dst = W1p + gid * 8;
#pragma unroll
    for (int e = 0; e < 8; e++) dst[e] = f2bf(W1[(ks * 32 + g * 8 + e) * FDIM + n]);
  } else {  // W2: 4*4*384 groups
    const int q = gid - 2048;
    const int ks = q / 1536;
    const int rem = q - ks * 1536;
    const int g = rem / 384;
    const int n = rem - g * 384;
    ushort* dst = W2p + q * 8;
#pragma unroll
    for (int e = 0; e < 8; e++) dst[e] = f2bf(W2[(ks * 32 + g * 8 + e) * PHI_DIM + n]);
  }
}

// ------- node MLP via MFMA: 625 blocks x 256 thr (4 waves), 16 nodes/block -------
// A layout (verified r17): row=lane&15, k=(lane>>4)*8+[0,8) ; B: col=lane&15, same k
// D: col=lane&15, row=(lane>>4)*4+reg
__global__ __launch_bounds__(256) void phi_kernel(
    const float* __restrict__ S, const float* __restrict__ b1, const float* __restrict__ b2,
    const float* __restrict__ vf, const int* __restrict__ idx_i, const int* __restrict__ idx_j,
    int* __restrict__ counts, const ushort* __restrict__ W1p, const ushort* __restrict__ W2p,
    char* __restrict__ tab) {
  __shared__ ushort Hb[16][136];  // padded: row stride 272 B
  __shared__ ushort Pb[16][392];  // padded: row stride 784 B
  const int t = threadIdx.x;
  const int lane = t & 63;
  const int wv = t >> 6;        // 0..3
  const int mrow = lane & 15;   // A-row (node) / B,D-col
  const int kg = lane >> 4;     // 0..3 (k-group)
  // fused: edge counting (2 edges/thread: 625*256*2 == NE)
  {
    const int e0 = (blockIdx.x * 256 + t) * 2;
    atomicAdd(&counts[jbucket(idx_j[e0]) * NN + idx_i[e0]], 1);
    atomicAdd(&counts[jbucket(idx_j[e0 + 1]) * NN + idx_i[e0 + 1]], 1);
  }
  const int n0 = blockIdx.x * 16;
  // A-frags from S (f32 -> bf16)
  bf16x8 sfrag[4];
#pragma unroll
  for (int ks = 0; ks < 4; ks++) {
    const float* sp = S + (size_t)(n0 + mrow) * FDIM + ks * 32 + kg * 8;
    float4 v0 = *(const float4*)sp;
    float4 v1 = *(const float4*)(sp + 4);
    uint w0 = ((uint)f2bf(v0.y) << 16) | f2bf(v0.x);
    uint w1 = ((uint)f2bf(v0.w) << 16) | f2bf(v0.z);
    uint w2 = ((uint)f2bf(v1.y) << 16) | f2bf(v1.x);
    uint w3 = ((uint)f2bf(v1.w) << 16) | f2bf(v1.z);
    sfrag[ks] = __builtin_bit_cast(bf16x8, make_uint4(w0, w1, w2, w3));
  }
  // layer 1: H = silu(S@W1 + b1), wave wv computes feat cols [wv*32, wv*32+32)
#pragma unroll
  for (int tile = 0; tile < 2; tile++) {
    const int nc = wv * 32 + tile * 16 + mrow;  // feature col
    f32x4 acc = {0.f, 0.f, 0.f, 0.f};
#pragma unroll
    for (int ks = 0; ks < 4; ks++) {
      bf16x8 bfrag = __builtin_bit_cast(
          bf16x8, *(const uint4*)(W1p + ((size_t)(ks * 4 + kg) * FDIM + nc) * 8));
      acc = __builtin_amdgcn_mfma_f32_16x16x32_bf16(sfrag[ks], bfrag, acc, 0, 0, 0);
    }
    const float bb = b1[nc];
#pragma unroll
    for (int r = 0; r < 4; r++) {
      const float x = acc[r] + bb;
      Hb[kg * 4 + r][nc] = f2bf(x / (1.0f + expf(-x)));
    }
  }
  __syncthreads();
  // layer 2: phi = H@W2 + b2, wave wv computes cols [wv*96, wv*96+96)
  bf16x8 hfrag[4];
#pragma unroll
  for (int ks = 0; ks < 4; ks++)
    hfrag[ks] = __builtin_bit_cast(bf16x8, *(const uint4*)&Hb[mrow][ks * 32 + kg * 8]);
#pragma unroll
  for (int tile = 0; tile < 6; tile++) {
    const int nc = wv * 96 + tile * 16 + mrow;  // phi col 0..383
    f32x4 acc = {0.f, 0.f, 0.f, 0.f};
#pragma unroll
    for (int ks = 0; ks < 4; ks++) {
      bf16x8 bfrag = __builtin_bit_cast(
          bf16x8, *(const uint4*)(W2p + ((size_t)(ks * 4 + kg) * PHI_DIM + nc) * 8));
      acc = __builtin_amdgcn_mfma_f32_16x16x32_bf16(hfrag[ks], bfrag, acc, 0, 0, 0);
    }
    const float bb = b2[nc];
#pragma unroll
    for (int r = 0; r < 4; r++) Pb[kg * 4 + r][nc] = f2bf(acc[r] + bb);
  }
  __syncthreads();
  // pack phase: w* = vf*·phi0 precompute + tab row assembly (16 nodes x 128 feats)
#pragma unroll
  for (int c = 0; c < 8; c++) {
    const int idx = c * 256 + t;
    const int nd = idx >> 7;
    const int f = idx & 127;
    const int node = n0 + nd;
    const float p0 = bf2f(Pb[nd][f]);
    const uint p1u = Pb[nd][f + 128];
    const ushort p2u = Pb[nd][f + 256];
    const float* src = vf + (size_t)node * (FDIM * 3) + f * 3;
    const uint wx = f2bf(src[0] * p0);
    const uint wy = f2bf(src[1] * p0);
    const uint wz = f2bf(src[2] * p0);
    char* pb = tab + (size_t)node * 1280;
    ((uint*)pb)[f] = (wy << 16) | wx;
    ((uint*)(pb + 512))[f] = (p1u << 16) | wz;
    ((ushort*)(pb + 1024))[f] = p2u;
  }
}

// ---------------- scan: per-block partials + block-sum scan ----------------
__global__ void scan1_kernel(const int* __restrict__ counts, int* __restrict__ offsets,
                             int* __restrict__ blocksums) {
  __shared__ int s[256];
  const int t = threadIdx.x;
  const int idx = blockIdx.x * 256 + t;
  const int c = counts[idx];  // region zero-padded to 40960
  s[t] = c;
  __syncthreads();
  for (int off = 1; off < 256; off <<= 1) {
    int v = (t >= off) ? s[t - off] : 0;
    __syncthreads();
    s[t] += v;
    __syncthreads();
  }
  if (idx < NKEY) offsets[idx] = s[t] - c;  // exclusive WITHIN block (partial)
  if (t == 255) blocksums[blockIdx.x] = s[255];
}

__global__ void scan2_kernel(int* __restrict__ blocksums, int* __restrict__ offsets) {
  __shared__ int s[256];
  const int t = threadIdx.x;  // 256 threads
  int v0 = (t < SCAN_BLOCKS) ? blocksums[t] : 0;
  s[t] = v0;
  __syncthreads();
  for (int off = 1; off < 256; off <<= 1) {
    int v = (t >= off) ? s[t - off] : 0;
    __syncthreads();
    s[t] += v;
    __syncthreads();
  }
  if (t < SCAN_BLOCKS) blocksums[t] = s[t] - v0;  // exclusive base per block
  if (t == 255) offsets[NKEY] = s[t];             // FINAL total = NE
}

// ---------------- stage CSR-ordered (bucket-major): jlist + 48-B records ----------------
__global__ void stage_kernel(const int* __restrict__ idx_i, const int* __restrict__ idx_j,
                             const float* __restrict__ cut, const float* __restrict__ dir,
                             const float* __restrict__ rbf, const int* __restrict__ offsets,
                             const int* __restrict__ blocksums, int* __restrict__ counts,
                             uint* __restrict__ edata, int* __restrict__ jlist) {
  int e = blockIdx.x * blockDim.x + threadIdx.x;
  if (e >= NE) return;
  const int j = idx_j[e];
  const int key = jbucket(j) * NN + idx_i[e];
  int pos = atomicSub(&counts[key], 1) - 1;
  const int slot = offsets[key] + blocksums[key >> 8] + pos;
  jlist[slot] = j;
  const float c = cut[e];
  uint w[12];
  w[0] = ((uint)f2bf(dir[e * 3 + 1]) << 16) | f2bf(dir[e * 3 + 0]);
  const float* rb = rbf + (size_t)e * NRBF;
#pragma unroll
  for (int r = 0; r < 10; r++) {
    uint lo = (uint)f2bf(rb[2 * r] * c);
    uint hi = (uint)f2bf(rb[2 * r + 1] * c);
    w[1 + r] = (hi << 16) | lo;
  }
  w[11] = ((uint)f2bf(dir[e * 3 + 2]) << 16) | f2bf(c);
  uint4* d = (uint4*)(edata + (size_t)slot * 12);
  d[0] = make_uint4(w[0], w[1], w[2], w[3]);
  d[1] = make_uint4(w[4], w[5], w[6], w[7]);
  d[2] = make_uint4(w[8], w[9], w[10], w[11]);
}

// ---- node: 1 node / 128-thread block, 4 bucket-segments, 2-deep pipeline ----
__global__ __launch_bounds__(128, 5) void node_kernel(
    const uint* __restrict__ edata, const int* __restrict__ jlist,
    const float* __restrict__ Wr, const float* __restrict__ br,
    const char* __restrict__ tab, const float* __restrict__ sf,
    const float* __restrict__ vf, const int* __restrict__ offsets,
    const int* __restrict__ blocksums, float* __restrict__ out) {
  const int f = threadIdx.x;  // 0..127
#if USE_DOT2
  bf16x2 wrA[11], wrB[11], wrC[11];
#pragma unroll
  for (int r = 0; r < 10; r++) {
    uint a = ((uint)f2bf(Wr[(2 * r + 1) * PHI_DIM + f]) << 16) | f2bf(Wr[(2 * r) * PHI_DIM + f]);
    uint b = ((uint)f2bf(Wr[(2 * r + 1) * PHI_DIM + f + 128]) << 16) |
             f2bf(Wr[(2 * r) * PHI_DIM + f + 128]);
    uint c = ((uint)f2bf(Wr[(2 * r + 1) * PHI_DIM + f + 256]) << 16) |
             f2bf(Wr[(2 * r) * PHI_DIM + f + 256]);
    wrA[r] = __builtin_bit_cast(bf16x2, a);
    wrB[r] = __builtin_bit_cast(bf16x2, b);
    wrC[r] = __builtin_bit_cast(bf16x2, c);
  }
  wrA[10] = __builtin_bit_cast(bf16x2, (uint)f2bf(br[f]));
  wrB[10] = __builtin_bit_cast(bf16x2, (uint)f2bf(br[f + 128]));
  wrC[10] = __builtin_bit_cast(bf16x2, (uint)f2bf(br[f + 256]));
#else
  float wrA[22], wrB[22], wrC[22];
#pragma unroll
  for (int r = 0; r < NRBF; r++) {
    wrA[r] = Wr[r * PHI_DIM + f];
    wrB[r] = Wr[r * PHI_DIM + f + 128];
    wrC[r] = Wr[r * PHI_DIM + f + 256];
  }
  wrA[20] = br[f];       wrA[21] = 0.f;
  wrB[20] = br[f + 128]; wrB[21] = 0.f;
  wrC[20] = br[f + 256]; wrC[21] = 0.f;
#endif
  const int n = blockIdx.x;
  const int f4 = f * 4;
  float ss = 0.f, ax = 0.f, ay = 0.f, az = 0.f;
  int cnt = 0;

  auto process = [&](uint4 e0, uint4 e1, uint4 e2, uint d0, uint d1, uint zu) {
    uint rbp[11] = {e0.y, e0.z, e0.w, e1.x, e1.y, e1.z, e1.w, e2.x, e2.y, e2.z, e2.w};
    const float dx = bflo(e0.x);
    const float dy = bfhi(e0.x);
    const float dz = bfhi(rbp[10]);
    float g0 = 0.f, g1 = 0.f, g2 = 0.f;
#if USE_DOT2
#pragma unroll
    for (int r = 0; r < 11; r++) {
      bf16x2 rp = __builtin_bit_cast(bf16x2, rbp[r]);
      g0 = __builtin_amdgcn_fdot2_f32_bf16(rp, wrA[r], g0, false);
      g1 = __builtin_amdgcn_fdot2_f32_bf16(rp, wrB[r], g1, false);
      g2 = __builtin_amdgcn_fdot2_f32_bf16(rp, wrC[r], g2, false);
    }
#else
#pragma unroll
    for (int r = 0; r < 11; r++) {
      float rlo = bflo(rbp[r]);
      float rhi = bfhi(rbp[r]);
      g0 += rlo * wrA[2 * r] + rhi * wrA[2 * r + 1];
      g1 += rlo * wrB[2 * r] + rhi * wrB[2 * r + 1];
      g2 += rlo * wrC[2 * r] + rhi * wrC[2 * r + 1];
    }
#endif
    const float vs = bflo(zu) * g2;
    ss += bfhi(d1) * g1;
    ax += bflo(d0) * g0 + vs * dx;
    ay += bfhi(d0) * g0 + vs * dy;
    az += bflo(d1) * g0 + vs * dz;
  };

  for (int b = 0; b < NBUCK; b++) {
    const int k0 = b * NN + n;
    const int beg = __builtin_amdgcn_readfirstlane(offsets[k0] + blocksums[k0 >> 8]);
    const int k1 = k0 + 1;
    const int end = __builtin_amdgcn_readfirstlane(
        (k1 < NKEY) ? (offsets[k1] + blocksums[k1 >> 8]) : offsets[NKEY]);
    cnt += end - beg;
    int p = beg;
    for (; p + 2 <= end; p += 2) {
      const int j0 = __builtin_amdgcn_readfirstlane(jlist[p]);
      const int j1 = __builtin_amdgcn_readfirstlane(jlist[p + 1]);
      const char* B0 = tab + (size_t)j0 * 1280;
      const char* B1 = tab + (size_t)j1 * 1280;
      const uint d00 = *(const uint*)(B0 + f4), d01 = *(const uint*)(B0 + 512 + f4);
      const uint z0 = *(const ushort*)(B0 + 1024 + f * 2);
      const uint d10 = *(const uint*)(B1 + f4), d11 = *(const uint*)(B1 + 512 + f4);
      const uint z1 = *(const ushort*)(B1 + 1024 + f * 2);
      const uint4* r0 = (const uint4*)(edata + (size_t)p * 12);
      const uint4* r1 = (const uint4*)(edata + (size_t)(p + 1) * 12);
      uint4 a0 = r0[0], a1 = r0[1], a2 = r0[2];
      uint4 b0 = r1[0], b1 = r1[1], b2 = r1[2];
      process(a0, a1, a2, d00, d01, z0);
      process(b0, b1, b2, d10, d11, z1);
    }
    if (p < end) {
      const int j0 = __builtin_amdgcn_readfirstlane(jlist[p]);
      const char* B0 = tab + (size_t)j0 * 1280;
      const uint d00 = *(const uint*)(B0 + f4), d01 = *(const uint*)(B0 + 512 + f4);
      const uint z0 = *(const ushort*)(B0 + 1024 + f * 2);
      const uint4* r0 = (const uint4*)(edata + (size_t)p * 12);
      process(r0[0], r0[1], r0[2], d00, d01, z0);
    }
  }

  const float inv = 1.0f / (float)cnt;
  out[(size_t)n * FDIM + f] = sf[(size_t)n * FDIM + f] + ss * inv;
  float* ov = out + (size_t)NN * FDIM + (size_t)n * (FDIM * 3) + f * 3;
  const float* iv = vf + (size_t)n * (FDIM * 3) + f * 3;
  ov[0] = iv[0] + ax * inv;
  ov[1] = iv[1] + ay * inv;
  ov[2] = iv[2] + az * inv;
}

extern "C" void kernel_launch(void* const* d_in, const int* in_sizes, int n_in,
                              void* d_out, int out_size, void* d_ws, size_t ws_size,
                              hipStream_t stream) {
  const int* idx_i = (const int*)d_in[0];
  const int* idx_j = (const int*)d_in[1];
  const float* rel_dir = (const float*)d_in[2];
  const float* cut = (const float*)d_in[3];
  const float* rbf = (const float*)d_in[4];
  const float* sf = (const float*)d_in[5];
  const float* vf = (const float*)d_in[6];
  const float* W1 = (const float*)d_in[7];
  const float* b1 = (const float*)d_in[8];
  const float* W2 = (const float*)d_in[9];
  const float* b2 = (const float*)d_in[10];
  const float* Wr = (const float*)d_in[11];
  const float* br = (const float*)d_in[12];
  float* out = (float*)d_out;

  // workspace layout (bytes):
  //   counts   : [0, 163840)            40960 ints (zero-padded; consumed by stage)
  //   offsets  : [163840, 327680)       40001 ints (PARTIAL; +blocksums[k>>8])
  //   blocksums: [327680, 328704)       256 ints
  //   edata    : [328704, 15688704)     320000 * 48 B
  //   tab      : [15688704, 28488704)   10000 * 1280 B
  //   jlist    : [28488704, 29768704)   320000 ints
  //   W1p      : [29768704, 29801472)   16384 ushort frag-packed
  //   W2p      : [29801472, 29899776)   49152 ushort frag-packed
  char* w = (char*)d_ws;
  int* counts = (int*)w;
  int* offsets = (int*)(w + 163840);
  int* blocksums = (int*)(w + 327680);
  uint* edata = (uint*)(w + 328704);
  char* tab = w + 15688704;
  int* jlist = (int*)(w + 28488704);
  ushort* W1p = (ushort*)(w + 29768704);
  ushort* W2p = (ushort*)(w + 29801472);

  hipMemsetAsync(w, 0, 163840, stream);  // zero counts only
  hipLaunchKernelGGL(wconv_kernel, dim3(32), dim3(256), 0, stream, W1, W2, W1p, W2p);
  hipLaunchKernelGGL(phi_kernel, dim3(NN / 16), dim3(256), 0, stream, sf, b1, b2, vf, idx_i,
                     idx_j, counts, W1p, W2p, tab);
  hipLaunchKernelGGL(scan1_kernel, dim3(SCAN_BLOCKS), dim3(256), 0, stream, counts, offsets,
                     blocksums);
  hipLaunchKernelGGL(scan2_kernel, dim3(1), dim3(256), 0, stream, blocksums, offsets);
  hipLaunchKernelGGL(stage_kernel, dim3((NE + 255) / 256), dim3(256), 0, stream, idx_i, idx_j,
                     cut, rel_dir, rbf, offsets, blocksums, counts, edata, jlist);
  hipLaunchKernelGGL(node_kernel, dim3(NN), dim3(128), 0, stream, edata, jlist, Wr, br, tab, sf,
                     vf, offsets, blocksums, out);
}